// Round 1
// baseline (4267.323 us; speedup 1.0000x reference)
//
#include <hip/hip_runtime.h>

// Problem constants
#define BB 64       // batch
#define TT 512      // time steps
#define II 128      // input dim
#define HH 512      // hidden
#define CC 5        // out classes

// ---------------------------------------------------------------------------
// Workspace layout (fits the proven 128MiB + 512KiB footprint):
//   R_A  (ws + 0,      64 MiB): ybuf0 = layer-0 output packet stream
//          [g=0..31][t=0..511][row=0..511] u64 packets, batches (2g, 2g+1),
//          each dword = float|0x80000000 (ready <=> both sign bits set).
//          Layer-1 output packets OVERLAY this region at slot t-2 (see below).
//   R_B  (ws + 64MiB,  64 MiB): xp0 floats [b][t][h] during launch A,
//          then memset-0 and reused as layer-2 packet stream
//          [gp][t][row][half] (16B/row, asym markers).
//   SIDE (ws + 128MiB, 256 KiB): layer-1 packets for t<2 (memset 0xFF).
//
// Packet conventions:
//   ybuf0 (scan0):   ready <=> bit31(lo) && bit31(hi); value = dword & 0x7fffffff
//   ybuf1/ybuf2:     ready <=> !bit31(lo) && bit31(hi)   (asymmetric marker)
//                    lo = raw float (relu => bit31==0), hi = float | bit31.
//   All initial states (zeros, 0xFF, stale scan0 packets) fail the asym check,
//   so every poll is self-validating -- no phase counters needed.
//
// Overlay safety (layer-1 packets over ybuf0[t-2]):
//   - intra-population spread <= 1 step (publish of t gated on consuming
//     partners' t-1), so ybuf0[t-2] was consumed by every fused partner
//     (read in tail of their step t-3) and by scan0 partners (scan0 always
//     >= fused+1) before any fused block can write it at step t.
//   - every state transition is marker-distinguishable, so even an unfenced
//     straggler read fails the ready check instead of reading garbage.
// ---------------------------------------------------------------------------

#define FPAD(v) ((((v) >> 5) * 36) + ((v) & 31))   // +4 pad per 32 floats (bank spread)
#define M31LO(u) __uint_as_float((unsigned int)(u) & 0x7fffffffu)
#define M31HI(u) __uint_as_float((unsigned int)((u) >> 32) & 0x7fffffffu)

struct FSh {                    // fused-layer block shared state (36.9 KB)
    float hbs[2][4][16 * 36];   // [buf][batch][FPAD(row)] own-layer h
    float ybs[2][4][16 * 36];   // [buf][batch][FPAD(row)] previous-layer y
    int written[8];
};
struct SSh {                    // scan0 block shared state (17.4 KB)
    float hbs[4][2][8 * 68];
    int written[8];
};
union ShU { FSh f; SSh s; };

__device__ __forceinline__ bool prdy(unsigned long long u, int set) {
    const unsigned int hi = (unsigned int)(u >> 63) & 1u;
    const unsigned int lo = (unsigned int)(u >> 31) & 1u;
    return set ? (hi && lo) : (hi && !lo);
}

// Packet address functions.
//  M==2: ybuf0 direct          (read y from scan0)
//  M==0: layer-1 overlay       (t>=2 -> ybuf0 slot t-2; t<2 -> SIDE)
//  M==1: flat 16B packets in R_B (layer-2 exchange / output)
template <int M>
__device__ __forceinline__ const unsigned long long* src_addr(
    const unsigned long long* mainb, const unsigned long long* sideb,
    int gp, int t, int v, int half)
{
    if constexpr (M == 2) {
        return mainb + (((size_t)(2 * gp + half) * 512 + t) * 512 + v);
    } else if constexpr (M == 0) {
        if (t >= 2) return mainb + (((size_t)(2 * gp + half) * 512 + (t - 2)) * 512 + v);
        return sideb + (((size_t)(gp * 2 + t) * 512 + v) * 2 + half);
    } else {
        return mainb + (((size_t)gp * 512 + t) * 512 + v) * 2 + half;
    }
}

// ---------------------------------------------------------------------------
// GEMM for layer-0 xproj (unchanged; ~fp32-roofline already)
// ---------------------------------------------------------------------------
__global__ __launch_bounds__(256) void gemm_bias_kernel(
    const float* __restrict__ A, const float* __restrict__ W,
    const float* __restrict__ b1, const float* __restrict__ b2,
    float* __restrict__ out, int K)
{
    __shared__ float As[16][132];
    __shared__ float Bs[16][132];
    const int tid = threadIdx.x;
    const int bm = blockIdx.x;
    const int bn = blockIdx.y;
    const int tx = tid & 15;
    const int ty = tid >> 4;
    const int lr = tid >> 2;
    const int lk = (tid & 3) << 2;

    const float* Ab = A + (size_t)bm * 128 * K;
    const float* Wb = W + (size_t)bn * 128 * K;

    float acc[8][8];
#pragma unroll
    for (int i = 0; i < 8; ++i)
#pragma unroll
        for (int j = 0; j < 8; ++j) acc[i][j] = 0.f;

    for (int k0 = 0; k0 < K; k0 += 16) {
        float4 a0 = *(const float4*)(Ab + (size_t)lr * K + k0 + lk);
        float4 a1 = *(const float4*)(Ab + (size_t)(lr + 64) * K + k0 + lk);
        float4 w0 = *(const float4*)(Wb + (size_t)lr * K + k0 + lk);
        float4 w1 = *(const float4*)(Wb + (size_t)(lr + 64) * K + k0 + lk);
        __syncthreads();
        As[lk + 0][lr] = a0.x; As[lk + 1][lr] = a0.y; As[lk + 2][lr] = a0.z; As[lk + 3][lr] = a0.w;
        As[lk + 0][lr + 64] = a1.x; As[lk + 1][lr + 64] = a1.y; As[lk + 2][lr + 64] = a1.z; As[lk + 3][lr + 64] = a1.w;
        Bs[lk + 0][lr] = w0.x; Bs[lk + 1][lr] = w0.y; Bs[lk + 2][lr] = w0.z; Bs[lk + 3][lr] = w0.w;
        Bs[lk + 0][lr + 64] = w1.x; Bs[lk + 1][lr + 64] = w1.y; Bs[lk + 2][lr + 64] = w1.z; Bs[lk + 3][lr + 64] = w1.w;
        __syncthreads();
#pragma unroll
        for (int k = 0; k < 16; ++k) {
            float4 av0 = *(const float4*)&As[k][ty * 8];
            float4 av1 = *(const float4*)&As[k][ty * 8 + 4];
            float4 bv0 = *(const float4*)&Bs[k][tx * 8];
            float4 bv1 = *(const float4*)&Bs[k][tx * 8 + 4];
            float a[8] = {av0.x, av0.y, av0.z, av0.w, av1.x, av1.y, av1.z, av1.w};
            float b[8] = {bv0.x, bv0.y, bv0.z, bv0.w, bv1.x, bv1.y, bv1.z, bv1.w};
#pragma unroll
            for (int i = 0; i < 8; ++i)
#pragma unroll
                for (int j = 0; j < 8; ++j)
                    acc[i][j] = fmaf(a[i], b[j], acc[i][j]);
        }
    }

    const int nb = bn * 128 + tx * 8;
    float bias[8];
#pragma unroll
    for (int j = 0; j < 8; ++j) bias[j] = b1[nb + j] + b2[nb + j];
#pragma unroll
    for (int i = 0; i < 8; ++i) {
        const size_t m = (size_t)bm * 128 + ty * 8 + i;
        float4 o0 = {acc[i][0] + bias[0], acc[i][1] + bias[1], acc[i][2] + bias[2], acc[i][3] + bias[3]};
        float4 o1 = {acc[i][4] + bias[4], acc[i][5] + bias[5], acc[i][6] + bias[6], acc[i][7] + bias[7]};
        *(float4*)(out + m * HH + nb) = o0;
        *(float4*)(out + m * HH + nb + 4) = o1;
    }
}

// ---------------------------------------------------------------------------
// Layer-0 scan body: the proven wave-autonomous protocol, retargeted at the
// full-length ybuf0 packet stream (self-validating sign-bit markers replace
// the 4-slot phase protocol; plain y-stores dropped -- packets ARE the output).
// g in [0,32): batches 2g,2g+1.  s in [0,8): rows s*64..s*64+63.
// ---------------------------------------------------------------------------
__device__ void scan0_body(ShU* sh, int g, int s,
                           const float* __restrict__ xp,
                           const float* __restrict__ Whh,
                           unsigned long long* __restrict__ ybuf0)
{
    const int tid  = threadIdx.x;
    const int lane = tid & 63;
    const int wv   = tid >> 6;             // wave 0..7
    const int rloc = lane >> 3;            // 0..7
    const int kseg = lane & 7;             // 0..7 (64-wide k-segment)
    const int R    = s * 64 + wv * 8 + rloc;

    const float* wr = Whh + (size_t)R * HH + kseg * 64;
    const float4 w0  = *(const float4*)(wr + 0);
    const float4 w1  = *(const float4*)(wr + 4);
    const float4 w2  = *(const float4*)(wr + 8);
    const float4 w3  = *(const float4*)(wr + 12);
    const float4 w4  = *(const float4*)(wr + 16);
    const float4 w5  = *(const float4*)(wr + 20);
    const float4 w6  = *(const float4*)(wr + 24);
    const float4 w7  = *(const float4*)(wr + 28);
    const float4 w8  = *(const float4*)(wr + 32);
    const float4 w9  = *(const float4*)(wr + 36);
    const float4 w10 = *(const float4*)(wr + 40);
    const float4 w11 = *(const float4*)(wr + 44);
    const float4 w12 = *(const float4*)(wr + 48);
    const float4 w13 = *(const float4*)(wr + 52);
    const float4 w14 = *(const float4*)(wr + 56);
    const float4 w15 = *(const float4*)(wr + 60);

    unsigned long long* gb = ybuf0 + (size_t)g * (512 * 512);   // [t][row]
    const int gb0 = g * 2, gb1 = g * 2 + 1;

    const int lds_w    = wv * 68 + lane;
    const int self_lds = s * 68 + wv * 8 + rloc;
    const bool pub     = (kseg == 0);
    const bool foreign = (wv != s);

    sh->s.hbs[0][0][lds_w] = 0.f;
    sh->s.hbs[0][1][lds_w] = 0.f;
    if (tid < 8) sh->s.written[tid] = 0;

    float xp0 = 0.f, xp1 = 0.f;
    if (pub) {
        xp0 = xp[(size_t)gb0 * TT * HH + R];
        xp1 = xp[(size_t)gb1 * TT * HH + R];
    }
    __syncthreads();

    for (int t = 0; t < TT; ++t) {
        if (t > 0) {
            for (;;) {
                int m = __hip_atomic_load(&sh->s.written[0], __ATOMIC_RELAXED,
                                          __HIP_MEMORY_SCOPE_WORKGROUP);
#pragma unroll
                for (int c = 1; c < 8; ++c) {
                    int wc = __hip_atomic_load(&sh->s.written[c], __ATOMIC_RELAXED,
                                               __HIP_MEMORY_SCOPE_WORKGROUP);
                    m = (wc < m) ? wc : m;
                }
                if (m >= t) break;
            }
            __threadfence_block();
        }

        const int bi = t & 3;
        float a0 = 0.f, a1 = 0.f, c0 = 0.f, c1 = 0.f;
        const float* h0p = &sh->s.hbs[bi][0][kseg * 68];
        const float* h1p = &sh->s.hbs[bi][1][kseg * 68];
#define STEP4(WQ, OFF)                                                   \
        {                                                                \
            float4 h0 = *(const float4*)(h0p + (OFF));                   \
            float4 h1 = *(const float4*)(h1p + (OFF));                   \
            a0 = fmaf(WQ.x, h0.x, a0); a1 = fmaf(WQ.y, h0.y, a1);        \
            a0 = fmaf(WQ.z, h0.z, a0); a1 = fmaf(WQ.w, h0.w, a1);        \
            c0 = fmaf(WQ.x, h1.x, c0); c1 = fmaf(WQ.y, h1.y, c1);        \
            c0 = fmaf(WQ.z, h1.z, c0); c1 = fmaf(WQ.w, h1.w, c1);       \
        }
        STEP4(w0, 0)   STEP4(w1, 4)   STEP4(w2, 8)   STEP4(w3, 12)
        STEP4(w4, 16)  STEP4(w5, 20)  STEP4(w6, 24)  STEP4(w7, 28)
        STEP4(w8, 32)  STEP4(w9, 36)  STEP4(w10, 40) STEP4(w11, 44)
        STEP4(w12, 48) STEP4(w13, 52) STEP4(w14, 56) STEP4(w15, 60)
#undef STEP4

        float A = a0 + a1, Bv = c0 + c1;
        A  += __shfl_xor(A, 1);  A  += __shfl_xor(A, 2);  A  += __shfl_xor(A, 4);
        Bv += __shfl_xor(Bv, 1); Bv += __shfl_xor(Bv, 2); Bv += __shfl_xor(Bv, 4);

        const int q = t + 1;
        if (pub) {
            const float hn0 = fmaxf(A + xp0, 0.f);
            const float hn1 = fmaxf(Bv + xp1, 0.f);
            const unsigned long long pkt =
                (unsigned long long)(__float_as_uint(hn0) | 0x80000000u) |
                ((unsigned long long)(__float_as_uint(hn1) | 0x80000000u) << 32);
            // publish EVERY step (fused layer needs t=511 too)
            __hip_atomic_store(gb + (size_t)t * 512 + R, pkt,
                               __ATOMIC_RELAXED, __HIP_MEMORY_SCOPE_AGENT);
            if (q < TT) {
                sh->s.hbs[q & 3][0][self_lds] = hn0;
                sh->s.hbs[q & 3][1][self_lds] = hn1;
                xp0 = xp[((size_t)gb0 * TT + q) * HH + R];
                xp1 = xp[((size_t)gb1 * TT + q) * HH + R];
            }
        }

        if (q < TT) {
            if (foreign) {
                const unsigned long long* pp = gb + (size_t)t * 512 + tid;
                unsigned long long u;
                for (;;) {
                    u = __hip_atomic_load(pp, __ATOMIC_RELAXED, __HIP_MEMORY_SCOPE_AGENT);
                    if (prdy(u, 1)) break;
                }
                sh->s.hbs[q & 3][0][lds_w] = M31LO(u);
                sh->s.hbs[q & 3][1][lds_w] = M31HI(u);
            }
            __threadfence_block();
            if (lane == 0)
                __hip_atomic_store(&sh->s.written[wv], q, __ATOMIC_RELAXED,
                                   __HIP_MEMORY_SCOPE_WORKGROUP);
        }
    }
}

// ---------------------------------------------------------------------------
// Fused recurrent layer: on-the-fly xproj (W_ih dot against previous layer's
// y-stream) + recurrence, 4 batches/block, 16-lane k-split, 16 slices/group.
// gp in [0,16): batches 4gp..4gp+3.  s in [0,16): rows s*32..s*32+31.
// Per wave: 4 rows; lanes (rloc=lane>>4, kseg=lane&15), 32-wide k-segments.
// Duties per step tail: every lane polls 2 y-packets (row tid, both halves)
// and -- on its half-wave's h-chunk (c = 2wv + (lane>>5), skipped if c==s) --
// 2 h-packets, all 4 polls issued per spin iteration (pipelined).
// ---------------------------------------------------------------------------
template <int YAM, int YSET, int HAM>
__device__ void fused_body(ShU* sh, const int gp, const int s,
                           const float* __restrict__ Whh,
                           const float* __restrict__ Wih,
                           const float* __restrict__ bih,
                           const float* __restrict__ bhh,
                           const unsigned long long* __restrict__ ysrc,
                           const unsigned long long* __restrict__ yside,
                           unsigned long long* __restrict__ hmain,
                           unsigned long long* __restrict__ hside)
{
    const int tid  = threadIdx.x;
    const int lane = tid & 63;
    const int wv   = tid >> 6;            // 0..7
    const int kseg = lane & 15;           // 0..15
    const int rloc = lane >> 4;           // 0..3
    const int R    = s * 32 + wv * 4 + rloc;
    const bool pub = (kseg == 0);

    const float* whp = Whh + (size_t)R * HH + kseg * 32;
    const float* wip = Wih + (size_t)R * HH + kseg * 32;
    float4 wh[8], wi[8];
#pragma unroll
    for (int i = 0; i < 8; ++i) {
        wh[i] = *(const float4*)(whp + 4 * i);
        wi[i] = *(const float4*)(wip + 4 * i);
    }
    const float bias = bih[R] + bhh[R];

    const int c      = 2 * wv + (lane >> 5);   // h-chunk duty 0..15
    const bool hduty = (c != s);
    const int hv     = c * 32 + (lane & 31);   // row for h-exchange duty
    const int v0     = tid;                    // row for y-source duty

    // prologue: h_0 = 0; fetch y[0]
#pragma unroll
    for (int b = 0; b < 4; ++b) sh->f.hbs[0][b][FPAD(v0)] = 0.f;
    {
        const unsigned long long* a0 = src_addr<YAM>(ysrc, yside, gp, 0, v0, 0);
        const unsigned long long* a1 = src_addr<YAM>(ysrc, yside, gp, 0, v0, 1);
        bool d0 = false, d1 = false;
        for (;;) {
            unsigned long long u0 = 0, u1 = 0;
            if (!d0) u0 = __hip_atomic_load(a0, __ATOMIC_RELAXED, __HIP_MEMORY_SCOPE_AGENT);
            if (!d1) u1 = __hip_atomic_load(a1, __ATOMIC_RELAXED, __HIP_MEMORY_SCOPE_AGENT);
            if (!d0 && prdy(u0, YSET)) {
                sh->f.ybs[0][0][FPAD(v0)] = M31LO(u0);
                sh->f.ybs[0][1][FPAD(v0)] = M31HI(u0);
                d0 = true;
            }
            if (!d1 && prdy(u1, YSET)) {
                sh->f.ybs[0][2][FPAD(v0)] = M31LO(u1);
                sh->f.ybs[0][3][FPAD(v0)] = M31HI(u1);
                d1 = true;
            }
            if (d0 && d1) break;
        }
    }
    if (tid < 8) sh->f.written[tid] = 0;
    __syncthreads();

    for (int t = 0; t < TT; ++t) {
        const int bi = t & 1;
        if (t > 0) {
            for (;;) {
                int m = __hip_atomic_load(&sh->f.written[0], __ATOMIC_RELAXED,
                                          __HIP_MEMORY_SCOPE_WORKGROUP);
#pragma unroll
                for (int k = 1; k < 8; ++k) {
                    int wk = __hip_atomic_load(&sh->f.written[k], __ATOMIC_RELAXED,
                                               __HIP_MEMORY_SCOPE_WORKGROUP);
                    m = (wk < m) ? wk : m;
                }
                if (m >= t) break;
            }
            __threadfence_block();
        }

        // dot: acc = W_hh . h  +  W_ih . y_prev   (4 batches)
        float s0[4] = {0.f, 0.f, 0.f, 0.f}, s1[4] = {0.f, 0.f, 0.f, 0.f};
        const float* hb = &sh->f.hbs[bi][0][kseg * 36];
        const float* yb = &sh->f.ybs[bi][0][kseg * 36];
#pragma unroll
        for (int i = 0; i < 8; ++i) {
            const float4 wh4 = wh[i], wi4 = wi[i];
#pragma unroll
            for (int b = 0; b < 4; ++b) {
                const float4 h4 = *(const float4*)(hb + b * 576 + 4 * i);
                const float4 y4 = *(const float4*)(yb + b * 576 + 4 * i);
                s0[b] = fmaf(wh4.x, h4.x, s0[b]); s1[b] = fmaf(wh4.y, h4.y, s1[b]);
                s0[b] = fmaf(wh4.z, h4.z, s0[b]); s1[b] = fmaf(wh4.w, h4.w, s1[b]);
                s0[b] = fmaf(wi4.x, y4.x, s0[b]); s1[b] = fmaf(wi4.y, y4.y, s1[b]);
                s0[b] = fmaf(wi4.z, y4.z, s0[b]); s1[b] = fmaf(wi4.w, y4.w, s1[b]);
            }
        }
        float A[4];
#pragma unroll
        for (int b = 0; b < 4; ++b) {
            A[b] = s0[b] + s1[b];
            A[b] += __shfl_xor(A[b], 1);
            A[b] += __shfl_xor(A[b], 2);
            A[b] += __shfl_xor(A[b], 4);
            A[b] += __shfl_xor(A[b], 8);
        }

        const int q = t + 1;
        if (pub) {
            float hn[4];
#pragma unroll
            for (int b = 0; b < 4; ++b) hn[b] = fmaxf(A[b] + bias, 0.f);
#pragma unroll
            for (int half = 0; half < 2; ++half) {
                const unsigned int lo = __float_as_uint(hn[half * 2]);             // bit31==0
                const unsigned int hi = __float_as_uint(hn[half * 2 + 1]) | 0x80000000u;
                const unsigned long long pkt =
                    (unsigned long long)lo | ((unsigned long long)hi << 32);
                unsigned long long* dst =
                    (unsigned long long*)src_addr<HAM>(hmain, hside, gp, t, R, half);
                __hip_atomic_store(dst, pkt, __ATOMIC_RELAXED, __HIP_MEMORY_SCOPE_AGENT);
            }
            if (q < TT) {
#pragma unroll
                for (int b = 0; b < 4; ++b) sh->f.hbs[q & 1][b][FPAD(R)] = hn[b];
            }
        }

        if (q < TT) {
            const int qb = q & 1;
            const unsigned long long* py0 = src_addr<YAM>(ysrc, yside, gp, q, v0, 0);
            const unsigned long long* py1 = src_addr<YAM>(ysrc, yside, gp, q, v0, 1);
            const unsigned long long* ph0 = src_addr<HAM>(hmain, hside, gp, t, hv, 0);
            const unsigned long long* ph1 = src_addr<HAM>(hmain, hside, gp, t, hv, 1);
            bool dy0 = false, dy1 = false, dh0 = !hduty, dh1 = !hduty;
            for (;;) {
                unsigned long long u0 = 0, u1 = 0, u2 = 0, u3 = 0;
                if (!dy0) u0 = __hip_atomic_load(py0, __ATOMIC_RELAXED, __HIP_MEMORY_SCOPE_AGENT);
                if (!dy1) u1 = __hip_atomic_load(py1, __ATOMIC_RELAXED, __HIP_MEMORY_SCOPE_AGENT);
                if (!dh0) u2 = __hip_atomic_load(ph0, __ATOMIC_RELAXED, __HIP_MEMORY_SCOPE_AGENT);
                if (!dh1) u3 = __hip_atomic_load(ph1, __ATOMIC_RELAXED, __HIP_MEMORY_SCOPE_AGENT);
                if (!dy0 && prdy(u0, YSET)) {
                    sh->f.ybs[qb][0][FPAD(v0)] = M31LO(u0);
                    sh->f.ybs[qb][1][FPAD(v0)] = M31HI(u0);
                    dy0 = true;
                }
                if (!dy1 && prdy(u1, YSET)) {
                    sh->f.ybs[qb][2][FPAD(v0)] = M31LO(u1);
                    sh->f.ybs[qb][3][FPAD(v0)] = M31HI(u1);
                    dy1 = true;
                }
                if (!dh0 && prdy(u2, 0)) {
                    sh->f.hbs[qb][0][FPAD(hv)] = M31LO(u2);
                    sh->f.hbs[qb][1][FPAD(hv)] = M31HI(u2);
                    dh0 = true;
                }
                if (!dh1 && prdy(u3, 0)) {
                    sh->f.hbs[qb][2][FPAD(hv)] = M31LO(u3);
                    sh->f.hbs[qb][3][FPAD(hv)] = M31HI(u3);
                    dh1 = true;
                }
                if (dy0 && dy1 && dh0 && dh1) break;
            }
            __threadfence_block();
            if (lane == 0)
                __hip_atomic_store(&sh->f.written[wv], q, __ATOMIC_RELAXED,
                                   __HIP_MEMORY_SCOPE_WORKGROUP);
        }
    }
}

// ---------------------------------------------------------------------------
// Launch A: blocks [0,256) = fused layer-1, [256,512) = layer-0 scan.
// 512 thr, VGPR capped at 128 (launch_bounds min-waves 4) => guaranteed
// 2 blocks/CU, all 512 co-resident. Partner blocks stride 16/32 => same XCD.
// ---------------------------------------------------------------------------
__global__ __launch_bounds__(512, 4) void pipeA_kernel(
    const float* __restrict__ xp0, const float* __restrict__ Whh0,
    unsigned long long* __restrict__ RA,
    const float* __restrict__ Whh1, const float* __restrict__ Wih1,
    const float* __restrict__ bih1, const float* __restrict__ bhh1,
    unsigned long long* __restrict__ SIDE)
{
    __shared__ ShU sh;
    const int bi = blockIdx.x;
    if (bi < 256) {
        // fused layer 1: y from ybuf0 (set-markers), h-exchange via overlay
        fused_body<2, 1, 0>(&sh, bi & 15, bi >> 4, Whh1, Wih1, bih1, bhh1,
                            RA, SIDE, RA, SIDE);
    } else {
        const int j = bi - 256;
        scan0_body(&sh, j & 31, j >> 5, xp0, Whh0, RA);
    }
}

// Launch B: layer-2 (y from layer-1 overlay stream -- complete, polls pass
// instantly; h-exchange + output = flat packets in R_B).
__global__ __launch_bounds__(512, 2) void layer2_kernel(
    const unsigned long long* __restrict__ RA,
    const unsigned long long* __restrict__ SIDE,
    const float* __restrict__ Whh2, const float* __restrict__ Wih2,
    const float* __restrict__ bih2, const float* __restrict__ bhh2,
    unsigned long long* __restrict__ RB)
{
    __shared__ ShU sh;
    const int bi = blockIdx.x;
    fused_body<0, 0, 1>(&sh, bi & 15, bi >> 4, Whh2, Wih2, bih2, bhh2,
                        RA, SIDE, RB, RB);
}

// ---------------------------------------------------------------------------
// Head: out[b][c] = sum_h y2[b][T-1][h] * W_out[c][h] + b_out[c]
// reads layer-2 packets (mask stolen sign bits).
// ---------------------------------------------------------------------------
__global__ __launch_bounds__(64) void head_kernel(
    const unsigned long long* __restrict__ y2, const float* __restrict__ Wout,
    const float* __restrict__ bout, float* __restrict__ out)
{
    const int bc = blockIdx.x;
    const int b = bc / CC, c = bc % CC;
    const int lane = threadIdx.x;
    const int gp = b >> 2, j = b & 3, half = j >> 1, odd = j & 1;
    const unsigned int* ybase =
        (const unsigned int*)(y2 + ((size_t)(gp * 512 + (TT - 1)) * 512) * 2);
    const float* wrow = Wout + (size_t)c * HH;
    float s = 0.f;
#pragma unroll
    for (int i = 0; i < HH / 64; ++i) {
        const int h = lane + 64 * i;
        const float v = __uint_as_float(ybase[(size_t)h * 4 + half * 2 + odd] & 0x7fffffffu);
        s = fmaf(v, wrow[h], s);
    }
#pragma unroll
    for (int off = 32; off > 0; off >>= 1) s += __shfl_down(s, off);
    if (lane == 0) out[bc] = s + bout[c];
}

// ---------------------------------------------------------------------------
extern "C" void kernel_launch(void* const* d_in, const int* in_sizes, int n_in,
                              void* d_out, int out_size, void* d_ws, size_t ws_size,
                              hipStream_t stream)
{
    (void)in_sizes; (void)n_in; (void)out_size; (void)ws_size;
    const float* x = (const float*)d_in[0];
    const float* W_ih[3] = {(const float*)d_in[1], (const float*)d_in[5], (const float*)d_in[9]};
    const float* W_hh[3] = {(const float*)d_in[2], (const float*)d_in[6], (const float*)d_in[10]};
    const float* b_ih[3] = {(const float*)d_in[3], (const float*)d_in[7], (const float*)d_in[11]};
    const float* b_hh[3] = {(const float*)d_in[4], (const float*)d_in[8], (const float*)d_in[12]};
    const float* W_out = (const float*)d_in[13];
    const float* b_out = (const float*)d_in[14];
    float* out = (float*)d_out;

    unsigned long long* RA  = (unsigned long long*)d_ws;                          // 64 MiB
    float*              XP  = (float*)((char*)d_ws + ((size_t)64 << 20));          // 64 MiB
    unsigned long long* RB  = (unsigned long long*)XP;
    unsigned long long* SIDE = (unsigned long long*)((char*)d_ws + ((size_t)128 << 20)); // 256 KiB

    (void)hipMemsetAsync(RA, 0, (size_t)64 << 20, stream);          // ybuf0 not-ready
    (void)hipMemsetAsync(SIDE, 0xFF, (size_t)32768 * 8, stream);    // side not-ready (asym)

    // layer-0 xproj (K=128) into R_B
    gemm_bias_kernel<<<dim3(256, 4, 1), 256, 0, stream>>>(x, W_ih[0], b_ih[0], b_hh[0], XP, II);

    // layers 0+1 pipelined (1-step lag), xproj-1 fused into the scan
    pipeA_kernel<<<512, 512, 0, stream>>>(XP, W_hh[0], RA,
                                          W_hh[1], W_ih[1], b_ih[1], b_hh[1], SIDE);

    // R_B: xp0 dead -> layer-2 packet stream (zeros = not-ready)
    (void)hipMemsetAsync(RB, 0, (size_t)64 << 20, stream);

    // layer 2 (xproj-2 fused; y-source fully materialized)
    layer2_kernel<<<256, 512, 0, stream>>>(RA, SIDE, W_hh[2], W_ih[2], b_ih[2], b_hh[2], RB);

    head_kernel<<<BB * CC, 64, 0, stream>>>(RB, W_out, b_out, out);
}

// Round 2
// 2817.049 us; speedup vs baseline: 1.5148x; 1.5148x over previous
//
#include <hip/hip_runtime.h>

// Problem constants
#define BB 64       // batch
#define TT 512      // time steps
#define II 128      // input dim
#define HH 512      // hidden
#define CC 5        // out classes

// ---------------------------------------------------------------------------
// GEMM: out[m][n] = sum_k A[m][k] * W[n][k] + b1[n] + b2[n]   (baseline, kept)
// ---------------------------------------------------------------------------
__global__ __launch_bounds__(256) void gemm_bias_kernel(
    const float* __restrict__ A, const float* __restrict__ W,
    const float* __restrict__ b1, const float* __restrict__ b2,
    float* __restrict__ out, int K)
{
    __shared__ float As[16][132];
    __shared__ float Bs[16][132];
    const int tid = threadIdx.x;
    const int bm = blockIdx.x;
    const int bn = blockIdx.y;
    const int tx = tid & 15;
    const int ty = tid >> 4;
    const int lr = tid >> 2;
    const int lk = (tid & 3) << 2;

    const float* Ab = A + (size_t)bm * 128 * K;
    const float* Wb = W + (size_t)bn * 128 * K;

    float acc[8][8];
#pragma unroll
    for (int i = 0; i < 8; ++i)
#pragma unroll
        for (int j = 0; j < 8; ++j) acc[i][j] = 0.f;

    for (int k0 = 0; k0 < K; k0 += 16) {
        float4 a0 = *(const float4*)(Ab + (size_t)lr * K + k0 + lk);
        float4 a1 = *(const float4*)(Ab + (size_t)(lr + 64) * K + k0 + lk);
        float4 w0 = *(const float4*)(Wb + (size_t)lr * K + k0 + lk);
        float4 w1 = *(const float4*)(Wb + (size_t)(lr + 64) * K + k0 + lk);
        __syncthreads();
        As[lk + 0][lr] = a0.x; As[lk + 1][lr] = a0.y; As[lk + 2][lr] = a0.z; As[lk + 3][lr] = a0.w;
        As[lk + 0][lr + 64] = a1.x; As[lk + 1][lr + 64] = a1.y; As[lk + 2][lr + 64] = a1.z; As[lk + 3][lr + 64] = a1.w;
        Bs[lk + 0][lr] = w0.x; Bs[lk + 1][lr] = w0.y; Bs[lk + 2][lr] = w0.z; Bs[lk + 3][lr] = w0.w;
        Bs[lk + 0][lr + 64] = w1.x; Bs[lk + 1][lr + 64] = w1.y; Bs[lk + 2][lr + 64] = w1.z; Bs[lk + 3][lr + 64] = w1.w;
        __syncthreads();
#pragma unroll
        for (int k = 0; k < 16; ++k) {
            float4 av0 = *(const float4*)&As[k][ty * 8];
            float4 av1 = *(const float4*)&As[k][ty * 8 + 4];
            float4 bv0 = *(const float4*)&Bs[k][tx * 8];
            float4 bv1 = *(const float4*)&Bs[k][tx * 8 + 4];
            float a[8] = {av0.x, av0.y, av0.z, av0.w, av1.x, av1.y, av1.z, av1.w};
            float b[8] = {bv0.x, bv0.y, bv0.z, bv0.w, bv1.x, bv1.y, bv1.z, bv1.w};
#pragma unroll
            for (int i = 0; i < 8; ++i)
#pragma unroll
                for (int j = 0; j < 8; ++j)
                    acc[i][j] = fmaf(a[i], b[j], acc[i][j]);
        }
    }

    const int nb = bn * 128 + tx * 8;
    float bias[8];
#pragma unroll
    for (int j = 0; j < 8; ++j) bias[j] = b1[nb + j] + b2[nb + j];
#pragma unroll
    for (int i = 0; i < 8; ++i) {
        const size_t m = (size_t)bm * 128 + ty * 8 + i;
        float4 o0 = {acc[i][0] + bias[0], acc[i][1] + bias[1], acc[i][2] + bias[2], acc[i][3] + bias[3]};
        float4 o1 = {acc[i][4] + bias[4], acc[i][5] + bias[5], acc[i][6] + bias[6], acc[i][7] + bias[7]};
        *(float4*)(out + m * HH + nb) = o0;
        *(float4*)(out + m * HH + nb + 4) = o1;
    }
}

// ---------------------------------------------------------------------------
// DPP reduction helpers (VALU pipe -- deliberately NOT __shfl, which lowers to
// ds_swizzle and would re-load the LDS pipe we are draining).
// Reduce over an aligned 8-lane group: xor1 (quad_perm [1,0,3,2]),
// xor2 (quad_perm [2,3,0,1]), then row_half_mirror (lane^7 within 8; after the
// first two stages every 4-lane quad holds the quad-sum, so ^7 lands in the
// other quad and completes the 8-sum in all lanes).
// ---------------------------------------------------------------------------
template <int CTRL>
__device__ __forceinline__ float dpp_add(float v) {
    const int t = __builtin_amdgcn_update_dpp(0, __float_as_int(v), CTRL, 0xf, 0xf, true);
    return v + __int_as_float(t);
}
__device__ __forceinline__ float reduce8(float v) {
    v = dpp_add<0xB1>(v);    // quad_perm [1,0,3,2]  == xor 1
    v = dpp_add<0x4E>(v);    // quad_perm [2,3,0,1]  == xor 2
    v = dpp_add<0x141>(v);   // row_half_mirror      == xor 4 (see above)
    return v;
}

// ---------------------------------------------------------------------------
// Recurrent scan, LDS-traffic-minimized dataflow. 256 blocks x 512 threads,
// blockIdx = s*32 + g (s = row slice 0..7, g = batch pair 0..31).
//
// WHY: round-1 established the period tracks LDS instrs/CU/step (baseline 256
// ds_read_b128 ~= 3100cy of the 3640cy period). This version cuts LDS traffic
// ~2.3x+ by changing the lane decomposition so h data is not re-read per wave:
//   lane = rgrp(=lane>>3)*8+khi(=lane&7); wave wv
//   rows:      R = s*64 + rgrp*8 .. +8        (8 rows/lane, 64 VGPR weights)
//   k-window:  [ (wv*8+khi)*8, +8 )           (8 floats/batch -> 4 b128 reads)
// Wave wv's k-window lies entirely in h-chunk wv = the chunk wave wv itself
// polls (or computes, if wv==s)  ==>  NO cross-wave h gate at all.
// Cross-khi reduction: DPP (VALU). Cross-wave reduction: parity-double-
// buffered LDS partial array P + per-wave flags; wave s (pub) gathers, adds
// xp (biases folded in by gemm), relu, publishes packets, writes y.
//
// Sync safety:
//  - global packets: 4 slots + phase bit, per-layer memset (baseline r8
//    protocol verbatim; distance-4 clobber proof carries -- publisher of q
//    gathered q-1 partials which required partners' q-1 publishes).
//  - P parity (2-deep): wave w overwrites P[par][w] at iter t+2; reaching
//    t+2 requires polling q=t+2 <= partner pub's t+1 publish <= partner's
//    wave-s flag <= partner's wave-s poll of q=t+1 <= OUR pub's t publish
//    <= our pub read P[par][w] at t. Proven distance-2.
//  - lh h-buffers are wave-PRIVATE (chunk w written+read only by wave w);
//    4-deep kept for margin.
// ---------------------------------------------------------------------------
__global__ __launch_bounds__(512)
__attribute__((amdgpu_waves_per_eu(2, 2)))
void scan_kernel(
    const float* __restrict__ xp, const float* __restrict__ Whh,
    float* __restrict__ y, unsigned long long* hbuf)
{
    __shared__ float lh[4][2][512];        // [buf][batch][h-elem] 16 KB
    __shared__ float P[2][8][64][2];       // [parity][wave][row][batch] 4 KB
    __shared__ int pflag[8];               // per-wave partial progress

    const int tid  = threadIdx.x;
    const int s    = blockIdx.x >> 5;      // slice: rows s*64..+64
    const int g    = blockIdx.x & 31;      // batches 2g, 2g+1
    const int lane = tid & 63;
    const int wv   = tid >> 6;
    const int rgrp = lane >> 3;            // 8-row group within slice
    const int khi  = lane & 7;             // k-subwindow within wave
    const int ks   = wv * 8 + khi;         // global k-window [ks*8, ks*8+8)

    // --- weights: rows s*64+rgrp*8+j (j=0..7), cols ks*8..+8 : 64 VGPRs ---
    const float* wb = Whh + (size_t)(s * 64 + rgrp * 8) * HH + ks * 8;
    float4 W0[8], W1[8];
#pragma unroll
    for (int j = 0; j < 8; ++j) {
        W0[j] = *(const float4*)(wb + (size_t)j * HH);
        W1[j] = *(const float4*)(wb + (size_t)j * HH + 4);
    }

    unsigned long long* gbase = hbuf + (size_t)g * 2048;  // [slot 0..3][512]
    const int gb0 = g * 2, gb1 = g * 2 + 1;
    const bool ispub = (wv == s);
    const int prow = s * 64 + lane;        // pub lane's global row

    // h_0 = 0 in buf 0 (each thread covers element tid, both batches)
    lh[0][0][tid] = 0.f;
    lh[0][1][tid] = 0.f;
    if (tid < 8) pflag[tid] = 0;

    float xq0 = 0.f, xq1 = 0.f;
    if (ispub) {
        xq0 = xp[(size_t)gb0 * TT * HH + prow];
        xq1 = xp[(size_t)gb1 * TT * HH + prow];
    }
    __syncthreads();   // one-time: LDS init visible

    for (int t = 0; t < TT; ++t) {
        const int bi = t & 3;
        const int par = t & 1;
        const int q = t + 1;

        // --- (1) window read (4 x ds_read_b128; 2-way bank alias = free) ---
        const float* h0p = &lh[bi][0][wv * 64 + khi * 8];
        const float* h1p = &lh[bi][1][wv * 64 + khi * 8];
        const float4 ha0 = *(const float4*)(h0p);
        const float4 ha1 = *(const float4*)(h0p + 4);
        const float4 hb0 = *(const float4*)(h1p);
        const float4 hb1 = *(const float4*)(h1p + 4);

        // --- (2) 128 FMA: 8 rows x 8 k x 2 batches ---
        float pa[8], pb[8];
#pragma unroll
        for (int j = 0; j < 8; ++j) {
            float u = W0[j].x * ha0.x;
            u = fmaf(W0[j].y, ha0.y, u); u = fmaf(W0[j].z, ha0.z, u); u = fmaf(W0[j].w, ha0.w, u);
            u = fmaf(W1[j].x, ha1.x, u); u = fmaf(W1[j].y, ha1.y, u);
            u = fmaf(W1[j].z, ha1.z, u); u = fmaf(W1[j].w, ha1.w, u);
            pa[j] = u;
            float v = W0[j].x * hb0.x;
            v = fmaf(W0[j].y, hb0.y, v); v = fmaf(W0[j].z, hb0.z, v); v = fmaf(W0[j].w, hb0.w, v);
            v = fmaf(W1[j].x, hb1.x, v); v = fmaf(W1[j].y, hb1.y, v);
            v = fmaf(W1[j].z, hb1.z, v); v = fmaf(W1[j].w, hb1.w, v);
            pb[j] = v;
        }

        // --- (3) DPP reduce over the 8 khi lanes (VALU pipe) ---
#pragma unroll
        for (int j = 0; j < 8; ++j) {
            pa[j] = reduce8(pa[j]);
            pb[j] = reduce8(pb[j]);
        }

        // --- (4) write per-wave partials + flag ---
        if (khi == 0) {
            float* pw = &P[par][wv][rgrp * 8][0];
            float4 o0 = {pa[0], pb[0], pa[1], pb[1]};
            float4 o1 = {pa[2], pb[2], pa[3], pb[3]};
            float4 o2 = {pa[4], pb[4], pa[5], pb[5]};
            float4 o3 = {pa[6], pb[6], pa[7], pb[7]};
            *(float4*)(pw + 0)  = o0;
            *(float4*)(pw + 4)  = o1;
            *(float4*)(pw + 8)  = o2;
            *(float4*)(pw + 12) = o3;
        }
        __threadfence_block();   // release: P visible before flag
        if (lane == 0)
            __hip_atomic_store(&pflag[wv], q, __ATOMIC_RELAXED,
                               __HIP_MEMORY_SCOPE_WORKGROUP);

        if (ispub) {
            // --- (5) gather: spin 8 flags, sum 8 wave-partials + xp, relu ---
            for (;;) {
                int m = __hip_atomic_load(&pflag[0], __ATOMIC_RELAXED,
                                          __HIP_MEMORY_SCOPE_WORKGROUP);
#pragma unroll
                for (int c = 1; c < 8; ++c) {
                    int wc = __hip_atomic_load(&pflag[c], __ATOMIC_RELAXED,
                                               __HIP_MEMORY_SCOPE_WORKGROUP);
                    m = (wc < m) ? wc : m;
                }
                if (m >= q) break;
            }
            __threadfence_block();   // acquire

            float s0 = xq0, s1 = xq1;   // xp already includes b_ih+b_hh
#pragma unroll
            for (int w = 0; w < 8; ++w) {
                const float2 pr = *(const float2*)&P[par][w][lane][0];
                s0 += pr.x;
                s1 += pr.y;
            }
            const float hn0 = fmaxf(s0, 0.f);
            const float hn1 = fmaxf(s1, 0.f);

            if (q < TT) {
                unsigned long long* slotp = gbase + (q & 3) * 512;
                const unsigned int phase = 1u ^ (((unsigned)(q - 1) >> 2) & 1u);
                const unsigned long long pkt =
                    (unsigned long long)(__float_as_uint(hn0) | (phase << 31)) |
                    ((unsigned long long)(__float_as_uint(hn1) | (phase << 31)) << 32);
                __hip_atomic_store(slotp + prow, pkt,
                                   __ATOMIC_RELAXED, __HIP_MEMORY_SCOPE_AGENT);
                // self chunk s for next step (wave-private)
                lh[q & 3][0][prow] = hn0;
                lh[q & 3][1][prow] = hn1;
                xq0 = xp[((size_t)gb0 * TT + q) * HH + prow];
                xq1 = xp[((size_t)gb1 * TT + q) * HH + prow];
            }
            y[((size_t)gb0 * TT + t) * HH + prow] = hn0;
            y[((size_t)gb1 * TT + t) * HH + prow] = hn1;
        } else if (q < TT) {
            // --- (6) poll own chunk wv (row tid) for next step ---
            const unsigned long long* pp = gbase + (q & 3) * 512 + tid;
            const unsigned int phase = 1u ^ (((unsigned)(q - 1) >> 2) & 1u);
            unsigned long long u;
            for (;;) {
                u = __hip_atomic_load(pp, __ATOMIC_RELAXED,
                                      __HIP_MEMORY_SCOPE_AGENT);
                if ((((unsigned int)(u >> 31) & 1u) == phase) &&
                    ((unsigned int)(u >> 63) == phase)) break;
            }
            lh[q & 3][0][tid] = __uint_as_float((unsigned int)u & 0x7fffffffu);
            lh[q & 3][1][tid] = __uint_as_float((unsigned int)(u >> 32) & 0x7fffffffu);
        }
    }
}

// ---------------------------------------------------------------------------
// Head: out[b][c] = sum_h y[b][T-1][h] * W_out[c][h] + b_out[c]   (baseline)
// ---------------------------------------------------------------------------
__global__ __launch_bounds__(64) void head_kernel(
    const float* __restrict__ y2, const float* __restrict__ Wout,
    const float* __restrict__ bout, float* __restrict__ out)
{
    const int bc = blockIdx.x;
    const int b = bc / CC, c = bc % CC;
    const int lane = threadIdx.x;
    const float* yrow = y2 + ((size_t)b * TT + (TT - 1)) * HH;
    const float* wrow = Wout + (size_t)c * HH;
    float s = 0.f;
#pragma unroll
    for (int i = 0; i < HH / 64; ++i)
        s = fmaf(yrow[lane + 64 * i], wrow[lane + 64 * i], s);
#pragma unroll
    for (int off = 32; off > 0; off >>= 1) s += __shfl_down(s, off);
    if (lane == 0) out[bc] = s + bout[c];
}

// ---------------------------------------------------------------------------
extern "C" void kernel_launch(void* const* d_in, const int* in_sizes, int n_in,
                              void* d_out, int out_size, void* d_ws, size_t ws_size,
                              hipStream_t stream)
{
    (void)in_sizes; (void)n_in; (void)out_size; (void)ws_size;
    const float* x = (const float*)d_in[0];
    const float* W_ih[3] = {(const float*)d_in[1], (const float*)d_in[5], (const float*)d_in[9]};
    const float* W_hh[3] = {(const float*)d_in[2], (const float*)d_in[6], (const float*)d_in[10]};
    const float* b_ih[3] = {(const float*)d_in[3], (const float*)d_in[7], (const float*)d_in[11]};
    const float* b_hh[3] = {(const float*)d_in[4], (const float*)d_in[8], (const float*)d_in[12]};
    const float* W_out = (const float*)d_in[13];
    const float* b_out = (const float*)d_in[14];
    float* out = (float*)d_out;

    // workspace layout (floats): Y, XP, hbuf (4 slots)
    float* ws   = (float*)d_ws;
    float* Y    = ws;                        // B*T*H
    float* XP   = ws + (size_t)BB * TT * HH; // B*T*H
    unsigned long long* hbuf = (unsigned long long*)(XP + (size_t)BB * TT * HH); // 32*4*512 packets

    const size_t hbuf_bytes = 32 * 4 * 512 * sizeof(unsigned long long);  // 512 KB
    const dim3 ggrid(256, 4, 1);

    // layer 0
    gemm_bias_kernel<<<ggrid, 256, 0, stream>>>(x, W_ih[0], b_ih[0], b_hh[0], XP, II);
    (void)hipMemsetAsync(hbuf, 0, hbuf_bytes, stream);   // phase-clean slate per layer
    scan_kernel<<<256, 512, 0, stream>>>(XP, W_hh[0], Y, hbuf);
    // layer 1
    gemm_bias_kernel<<<ggrid, 256, 0, stream>>>(Y, W_ih[1], b_ih[1], b_hh[1], XP, HH);
    (void)hipMemsetAsync(hbuf, 0, hbuf_bytes, stream);
    scan_kernel<<<256, 512, 0, stream>>>(XP, W_hh[1], Y, hbuf);
    // layer 2
    gemm_bias_kernel<<<ggrid, 256, 0, stream>>>(Y, W_ih[2], b_ih[2], b_hh[2], XP, HH);
    (void)hipMemsetAsync(hbuf, 0, hbuf_bytes, stream);
    scan_kernel<<<256, 512, 0, stream>>>(XP, W_hh[2], Y, hbuf);
    // head
    head_kernel<<<BB * CC, 64, 0, stream>>>(Y, W_out, b_out, out);
}